// Round 8
// baseline (976.418 us; speedup 1.0000x reference)
//
#include <hip/hip_runtime.h>
#include <hip/hip_bf16.h>
#include <cstddef>

#define IMW   96
#define HWSZ  (IMW*IMW)       // 9216
#define CTOT  512
#define CHG   256             // channels per group
#define NBATCH 8
#define ROWP  104             // padded LDS row stride (ushorts)
#define BUFE  (IMW*ROWP)      // 9984 ushorts per LDS plane buffer
#define XT_LD 280             // mix staging stride (ushorts)
#define TO_LD 76              // mix transpose stride (ushorts): 152B, 8/16B aligned, 2-way banks

typedef short  bf16x8  __attribute__((ext_vector_type(8)));
typedef float  f32x4   __attribute__((ext_vector_type(4)));
typedef unsigned short ushort8v __attribute__((ext_vector_type(8)));

// packed f32x2 -> bf16x2 (v_cvt_pk_bf16_f32, RNE); lo in bits 0..15
__device__ __forceinline__ unsigned pk2(float lo, float hi) {
    union { __hip_bfloat162 h; unsigned u; } v;
    v.h = __float22bfloat162_rn(make_float2(lo, hi));
    return v.u;
}
__device__ __forceinline__ float bf2f(ushort u) {
    union { unsigned u; float f; } v; v.u = ((unsigned)u) << 16;
    return v.f;
}

// ---- tiny: convert w_mix (2x256x256 fp32) to bf16 once per launch ----
__global__ __launch_bounds__(256) void wconv_kernel(const float* __restrict__ w,
                                                    unsigned* __restrict__ wbf) {
    const int i = blockIdx.x * 256 + threadIdx.x;   // pair index
    wbf[i] = pk2(w[2 * i], w[2 * i + 1]);
}

// ---------------- kernel 1: grouped 1x1 conv + shuffle, bf16 MFMA ----------------
// XB=0: x fp32; XB=1: x bf16 state. Epilogue transposes acc through LDS so global
// stores are 8 x 128B fully-covered lines per instruction.
template<bool XB>
__global__ __launch_bounds__(256, 3) void mix_mfma(
    const void* __restrict__ xin, const ushort* __restrict__ wbf,
    ushort* __restrict__ h)
{
    const int pt = blockIdx.x * 64;
    const int b  = blockIdx.y >> 1, g = blockIdx.y & 1;
    const size_t xoff = ((size_t)b * CTOT + (size_t)g * CHG) * HWSZ;
    const ushort* wg = wbf + (size_t)g * CHG * CHG;
    ushort* hb = h + (size_t)b * CTOT * HWSZ;

    __shared__ ushort XtBuf[19456];   // 38.9 KB: staging [64][280] then transpose [256][76]

    const int t  = threadIdx.x;
    const int tq = t & 15;             // pixel quad
    const int tk = t >> 4;             // k-pair selector

    #pragma unroll
    for (int it = 0; it < 8; ++it) {   // covers all k
        const int k = 32 * it + 2 * tk;
        unsigned u0, u1, u2, u3;
        if constexpr (XB) {
            const ushort* xb = (const ushort*)xin + xoff;
            ushort4 a0 = *(const ushort4*)&xb[(size_t)k       * HWSZ + pt + 4 * tq];
            ushort4 a1 = *(const ushort4*)&xb[(size_t)(k + 1) * HWSZ + pt + 4 * tq];
            u0 = (unsigned)a0.x | ((unsigned)a1.x << 16);
            u1 = (unsigned)a0.y | ((unsigned)a1.y << 16);
            u2 = (unsigned)a0.z | ((unsigned)a1.z << 16);
            u3 = (unsigned)a0.w | ((unsigned)a1.w << 16);
        } else {
            const float* xb = (const float*)xin + xoff;
            float4 a0 = *(const float4*)&xb[(size_t)k       * HWSZ + pt + 4 * tq];
            float4 a1 = *(const float4*)&xb[(size_t)(k + 1) * HWSZ + pt + 4 * tq];
            u0 = pk2(a0.x, a1.x);
            u1 = pk2(a0.y, a1.y);
            u2 = pk2(a0.z, a1.z);
            u3 = pk2(a0.w, a1.w);
        }
        *(unsigned*)&XtBuf[(4 * tq + 0) * XT_LD + k] = u0;
        *(unsigned*)&XtBuf[(4 * tq + 1) * XT_LD + k] = u1;
        *(unsigned*)&XtBuf[(4 * tq + 2) * XT_LD + k] = u2;
        *(unsigned*)&XtBuf[(4 * tq + 3) * XT_LD + k] = u3;
    }
    __syncthreads();

    const int wv  = t >> 6;            // wave -> 64 o-channels
    const int ln  = t & 63;
    const int row = ln & 15;
    const int kb  = ln >> 4;

    f32x4 acc[4][4];
    #pragma unroll
    for (int m = 0; m < 4; ++m)
        #pragma unroll
        for (int n = 0; n < 4; ++n)
            acc[m][n] = (f32x4){0.f, 0.f, 0.f, 0.f};

    #pragma unroll
    for (int ks = 0; ks < 8; ++ks) {
        bf16x8 Xf[4], Wf[4];
        #pragma unroll
        for (int m = 0; m < 4; ++m)    // A operand: X^T[pixel=16m+row][k]
            Xf[m] = *(const bf16x8*)&XtBuf[(16 * m + row) * XT_LD + 32 * ks + 8 * kb];
        #pragma unroll
        for (int n = 0; n < 4; ++n)    // B operand: W^T[k][o]
            Wf[n] = *(const bf16x8*)&wg[(size_t)(64 * wv + 16 * n + row) * CHG + 32 * ks + 8 * kb];
        #pragma unroll
        for (int m = 0; m < 4; ++m)
            #pragma unroll
            for (int n = 0; n < 4; ++n)
                acc[m][n] = __builtin_amdgcn_mfma_f32_16x16x32_bf16(Xf[m], Wf[n], acc[m][n], 0, 0, 0);
    }

    // epilogue: acc -> LDS transpose [o][pixel] -> coalesced 128B-line stores
    __syncthreads();   // all Xf reads done; reuse buffer
    #pragma unroll
    for (int m = 0; m < 4; ++m) {
        #pragma unroll
        for (int n = 0; n < 4; ++n) {
            const int o = 64 * wv + 16 * n + row;
            *(uint2*)&XtBuf[o * TO_LD + 16 * m + 4 * kb] =
                make_uint2(pk2(acc[m][n][0], acc[m][n][1]), pk2(acc[m][n][2], acc[m][n][3]));
        }
    }
    __syncthreads();
    const int o8i = t >> 3;            // 0..31
    const int px8 = (t & 7) * 8;       // 0..56
    #pragma unroll
    for (int j = 0; j < 8; ++j) {
        const int o2 = o8i + 32 * j;
        const int c  = 2 * o2 + g;     // channel shuffle folded
        uint4 v = *(const uint4*)&XtBuf[o2 * TO_LD + px8];
        *(uint4*)&hb[(size_t)c * HWSZ + pt + px8] = v;
    }
}

// ------- kernel 2: PERSISTENT fused dwconv3x3 + IN + affine + GELU + gate + update -------
// grid = 512 blocks (one channel c each); each block walks its 8 batch-planes with a
// register->LDS double-buffered pipeline (sh/sx x2 = 80KB -> 2 blocks/CU).
// XB: cur bf16; PB: prev bf16; EQ: prev==cur; OB: out bf16.
// Alias safety (t2: out buffer == prev buffer): pv of plane q is prefetched by the same
// thread that later stores plane q, and the store value depends on the loaded pv.
template<bool XB, bool PB, bool EQ, bool OB>
__global__ __launch_bounds__(576, 5) void plane_kernel(
    const ushort* __restrict__ hmid,
    const void* __restrict__ xcur, const void* __restrict__ xprev,
    const float* __restrict__ wdw,
    const float* __restrict__ gammas, const float* __restrict__ betas,
    const float* __restrict__ alphap, int t,
    void* __restrict__ out)
{
    const int tid = threadIdx.x;
    const int r   = tid / 6;            // row 0..95
    const int s6  = tid - r * 6;        // segment 0..5
    const int x0  = s6 * 16;
    const int pix = r * IMW + x0;
    const int c   = blockIdx.x;         // channel

    __shared__ ushort lds[4 * BUFE];    // [sh0][sh1][sx0][sx1], ~78 KB
    __shared__ float  red[32];

    float w9[9];
    #pragma unroll
    for (int i = 0; i < 9; ++i) w9[i] = wdw[c * 9 + i];
    const float gam   = gammas[t * CTOT + c];
    const float be    = betas[t * CTOT + c];
    const float alpha = alphap[0];

    ushort8v cpr0, cpr1;                // current pv, bf16 raw (unused if EQ)

    // ---- prologue: stage plane 0 into buffer 0 ----
    {
        const size_t off = (size_t)c * HWSZ;   // b = 0
        const uint4* hs = (const uint4*)(hmid + off + (size_t)r * IMW);
        uint4 h0 = hs[2 * s6], h1 = hs[2 * s6 + 1];
        uint4* hd = (uint4*)(lds + r * ROWP);
        hd[2 * s6] = h0; hd[2 * s6 + 1] = h1;
        if constexpr (XB) {
            const ushort8v* s = (const ushort8v*)((const ushort*)xcur + off + pix);
            ushort8v a = s[0], bq = s[1];
            ushort8v* xd = (ushort8v*)(lds + 2 * BUFE + r * ROWP + x0);
            xd[0] = a; xd[1] = bq;
        } else {
            const float4* s = (const float4*)((const float*)xcur + off + pix);
            float4 v0 = s[0], v1 = s[1], v2 = s[2], v3 = s[3];
            uint4* xd = (uint4*)(lds + 2 * BUFE + r * ROWP + x0);
            xd[0] = make_uint4(pk2(v0.x, v0.y), pk2(v0.z, v0.w), pk2(v1.x, v1.y), pk2(v1.z, v1.w));
            xd[1] = make_uint4(pk2(v2.x, v2.y), pk2(v2.z, v2.w), pk2(v3.x, v3.y), pk2(v3.z, v3.w));
        }
        if constexpr (!EQ) {
            if constexpr (PB) {
                const ushort8v* s = (const ushort8v*)((const ushort*)xprev + off + pix);
                cpr0 = s[0]; cpr1 = s[1];
            } else {
                const float4* s = (const float4*)((const float*)xprev + off + pix);
                float4 v0 = s[0], v1 = s[1], v2 = s[2], v3 = s[3];
                uint4 t0 = make_uint4(pk2(v0.x, v0.y), pk2(v0.z, v0.w), pk2(v1.x, v1.y), pk2(v1.z, v1.w));
                uint4 t1 = make_uint4(pk2(v2.x, v2.y), pk2(v2.z, v2.w), pk2(v3.x, v3.y), pk2(v3.z, v3.w));
                cpr0 = *(ushort8v*)&t0; cpr1 = *(ushort8v*)&t1;
            }
        }
    }
    __syncthreads();

    for (int i = 0; i < NBATCH; ++i) {
        const size_t off  = ((size_t)i * CTOT + c) * HWSZ;
        const bool  more  = (i + 1 < NBATCH);
        const int   cur   = i & 1, nxt = cur ^ 1;
        const ushort* shc = lds + cur * BUFE;
        const ushort* sxc = lds + (2 + cur) * BUFE;

        // ---- issue next-plane prefetch loads ----
        uint4    nh0, nh1;
        ushort8v nxr0, nxr1;
        ushort8v npr0, npr1;
        if (more) {
            const size_t noff = off + (size_t)CTOT * HWSZ;
            const uint4* hs = (const uint4*)(hmid + noff + (size_t)r * IMW);
            nh0 = hs[2 * s6]; nh1 = hs[2 * s6 + 1];
            if constexpr (XB) {
                const ushort8v* s = (const ushort8v*)((const ushort*)xcur + noff + pix);
                nxr0 = s[0]; nxr1 = s[1];
            } else {
                const float4* s = (const float4*)((const float*)xcur + noff + pix);
                float4 v0 = s[0], v1 = s[1], v2 = s[2], v3 = s[3];
                uint4 t0 = make_uint4(pk2(v0.x, v0.y), pk2(v0.z, v0.w), pk2(v1.x, v1.y), pk2(v1.z, v1.w));
                uint4 t1 = make_uint4(pk2(v2.x, v2.y), pk2(v2.z, v2.w), pk2(v3.x, v3.y), pk2(v3.z, v3.w));
                nxr0 = *(ushort8v*)&t0; nxr1 = *(ushort8v*)&t1;
            }
            if constexpr (!EQ) {
                if constexpr (PB) {
                    const ushort8v* s = (const ushort8v*)((const ushort*)xprev + noff + pix);
                    npr0 = s[0]; npr1 = s[1];
                } else {
                    const float4* s = (const float4*)((const float*)xprev + noff + pix);
                    float4 v0 = s[0], v1 = s[1], v2 = s[2], v3 = s[3];
                    uint4 t0 = make_uint4(pk2(v0.x, v0.y), pk2(v0.z, v0.w), pk2(v1.x, v1.y), pk2(v1.z, v1.w));
                    uint4 t1 = make_uint4(pk2(v2.x, v2.y), pk2(v2.z, v2.w), pk2(v3.x, v3.y), pk2(v3.z, v3.w));
                    npr0 = *(ushort8v*)&t0; npr1 = *(ushort8v*)&t1;
                }
            }
        }

        // ---- depthwise 3x3 from sh[cur] ----
        float conv[16];
        #pragma unroll
        for (int q = 0; q < 16; ++q) conv[q] = 0.f;
        #pragma unroll
        for (int ky = 0; ky < 3; ++ky) {
            const int yy = r + ky - 1;
            if ((unsigned)yy < IMW) {
                const ushort* rp = shc + yy * ROWP + x0;
                float f[18];
                ushort8v a = *(const ushort8v*)rp;
                ushort8v bq = *(const ushort8v*)(rp + 8);
                f[0]  = (s6 > 0) ? bf2f(rp[-1]) : 0.f;
                f[17] = (s6 < 5) ? bf2f(rp[16]) : 0.f;
                #pragma unroll
                for (int j = 0; j < 8; ++j) { f[1 + j] = bf2f(a[j]); f[9 + j] = bf2f(bq[j]); }
                const float w0 = w9[3 * ky], w1 = w9[3 * ky + 1], w2 = w9[3 * ky + 2];
                #pragma unroll
                for (int q = 0; q < 16; ++q)
                    conv[q] = fmaf(w0, f[q], fmaf(w1, f[q + 1], fmaf(w2, f[q + 2], conv[q])));
            }
        }

        // ---- stage prefetched next plane into buffer nxt (no readers of nxt exist) ----
        if (more) {
            uint4* hd = (uint4*)(lds + nxt * BUFE + r * ROWP);
            hd[2 * s6] = nh0; hd[2 * s6 + 1] = nh1;
            ushort8v* xd = (ushort8v*)(lds + (2 + nxt) * BUFE + r * ROWP + x0);
            xd[0] = nxr0; xd[1] = nxr1;
        }

        // ---- instance-norm moments ----
        float s = 0.f, s2 = 0.f;
        #pragma unroll
        for (int q = 0; q < 16; ++q) { s += conv[q]; s2 = fmaf(conv[q], conv[q], s2); }
        #pragma unroll
        for (int o = 32; o; o >>= 1) {
            s  += __shfl_down(s, o, 64);
            s2 += __shfl_down(s2, o, 64);
        }
        const int wv = tid >> 6;
        if ((tid & 63) == 0) { red[wv] = s; red[16 + wv] = s2; }
        __syncthreads();                   // B2
        float ssum = 0.f, s2sum = 0.f;
        #pragma unroll
        for (int q = 0; q < 9; ++q) { ssum += red[q]; s2sum += red[16 + q]; }
        const float mu   = ssum * (1.f / HWSZ);
        const float var  = fmaxf(s2sum * (1.f / HWSZ) - mu * mu, 0.f);
        const float rsig = rsqrtf(var + 1e-5f);
        const float ga   = gam * rsig;

        // ---- tail: gate from sx[cur], GELU, residual update, store ----
        float xw[24];   // x window: px x0-8 .. x0+15 (bf16 via LDS)
        {
            const int lx = (x0 == 0) ? (IMW - 8) : (x0 - 8);
            ushort8v hl = *(const ushort8v*)(sxc + r * ROWP + lx);
            ushort8v c0 = *(const ushort8v*)(sxc + r * ROWP + x0);
            ushort8v c1 = *(const ushort8v*)(sxc + r * ROWP + x0 + 8);
            #pragma unroll
            for (int j = 0; j < 8; ++j) {
                xw[j] = bf2f(hl[j]); xw[8 + j] = bf2f(c0[j]); xw[16 + j] = bf2f(c1[j]);
            }
        }
        float gt[16];
        #pragma unroll
        for (int q = 0; q < 16; ++q) gt[q] = 0.f;
        #pragma unroll
        for (int dd = 0; dd < 3; ++dd) {
            const int d = 1 << dd;
            int ym = r - d; if (ym < 0) ym += IMW;
            ushort8v u0 = *(const ushort8v*)(sxc + ym * ROWP + x0);
            ushort8v u1 = *(const ushort8v*)(sxc + ym * ROWP + x0 + 8);
            #pragma unroll
            for (int q = 0; q < 8; ++q) {
                gt[q]     += fabsf(xw[8 + q]  - bf2f(u0[q])) + fabsf(xw[8 + q]  - xw[8 + q - d]);
                gt[8 + q] += fabsf(xw[16 + q] - bf2f(u1[q])) + fabsf(xw[16 + q] - xw[16 + q - d]);
            }
        }
        #pragma unroll
        for (int half = 0; half < 2; ++half) {
            float o8[8];
            #pragma unroll
            for (int q = 0; q < 8; ++q) {
                const int ii = 8 * half + q;
                const float xvi  = xw[8 + ii];
                const float eg   = __expf(gt[ii] * (-1.f / 3.f));
                const float gate = __builtin_amdgcn_rcpf(1.f + eg);
                const float hn   = fmaf(conv[ii] - mu, ga, be);
                const float z    = 0.7978845608f * fmaf(0.044715f * hn * hn, hn, hn);
                const float e2   = __expf(2.f * z);
                const float th   = 1.f - 2.f * __builtin_amdgcn_rcpf(e2 + 1.f);
                const float gel  = 0.5f * hn * (1.f + th);
                if constexpr (EQ) {
                    o8[q] = fmaf(gate, gel, xvi);                       // x - x_prev == 0
                } else {
                    const float pvv = bf2f(half ? cpr1[q] : cpr0[q]);
                    o8[q] = fmaf(alpha, xvi - pvv, fmaf(gate, gel, xvi));
                }
            }
            if constexpr (OB) {
                uint4 u = make_uint4(pk2(o8[0], o8[1]), pk2(o8[2], o8[3]),
                                     pk2(o8[4], o8[5]), pk2(o8[6], o8[7]));
                *(uint4*)((ushort*)out + off + pix + 8 * half) = u;
            } else {
                float* op = (float*)out + off + pix + 8 * half;
                *(float4*)op       = make_float4(o8[0], o8[1], o8[2], o8[3]);
                *(float4*)(op + 4) = make_float4(o8[4], o8[5], o8[6], o8[7]);
            }
        }

        if (more) {
            __syncthreads();               // tail reads of [cur] done before next staging
            if constexpr (!EQ) { cpr0 = npr0; cpr1 = npr1; }
        }
    }
}

extern "C" void kernel_launch(void* const* d_in, const int* in_sizes, int n_in,
                              void* d_out, int out_size, void* d_ws, size_t ws_size,
                              hipStream_t stream) {
    const float* x0     = (const float*)d_in[0];
    const float* wmix   = (const float*)d_in[1];
    const float* wdw    = (const float*)d_in[2];
    const float* gammas = (const float*)d_in[3];
    const float* betas  = (const float*)d_in[4];
    const float* alphap = (const float*)d_in[5];

    const size_t NELEM = (size_t)NBATCH * CTOT * HWSZ;   // 37,748,736
    float*  D   = (float*)d_out;                          // final x4 (fp32)
    char*   ws  = (char*)d_ws;
    ushort* X1b = (ushort*)ws;                            // x1, then x3 (bf16)
    ushort* X2b = (ushort*)(ws + NELEM * 2);              // x2 (bf16)
    ushort* Hb  = (ushort*)(ws + NELEM * 4);              // mix output (bf16)
    ushort* Wbf = (ushort*)(ws + NELEM * 6);              // w_mix bf16 (256 KB)

    wconv_kernel<<<256, 256, 0, stream>>>(wmix, (unsigned*)Wbf);

    dim3 mgrid(HWSZ / 64, NBATCH * 2);   // (144, 16)

    // t=0: cur=prev=x0 (fp32) -> X1b (bf16)
    mix_mfma<false><<<mgrid, 256, 0, stream>>>(x0, Wbf, Hb);
    plane_kernel<false, false, true, true><<<CTOT, 576, 0, stream>>>(
        Hb, x0, x0, wdw, gammas, betas, alphap, 0, X1b);
    // t=1: cur=X1b prev=x0 (fp32) -> X2b (bf16)
    mix_mfma<true><<<mgrid, 256, 0, stream>>>(X1b, Wbf, Hb);
    plane_kernel<true, false, false, true><<<CTOT, 576, 0, stream>>>(
        Hb, X1b, x0, wdw, gammas, betas, alphap, 1, X2b);
    // t=2: cur=X2b prev=X1b -> X1b (same-thread read-before-write alias)
    mix_mfma<true><<<mgrid, 256, 0, stream>>>(X2b, Wbf, Hb);
    plane_kernel<true, true, false, true><<<CTOT, 576, 0, stream>>>(
        Hb, X2b, X1b, wdw, gammas, betas, alphap, 2, X1b);
    // t=3: cur=X1b(x3) prev=X2b -> D (fp32 final)
    mix_mfma<true><<<mgrid, 256, 0, stream>>>(X1b, Wbf, Hb);
    plane_kernel<true, true, false, false><<<CTOT, 576, 0, stream>>>(
        Hb, X1b, X2b, wdw, gammas, betas, alphap, 3, D);
}

// Round 9
// 636.367 us; speedup vs baseline: 1.5344x; 1.5344x over previous
//
#include <hip/hip_runtime.h>
#include <hip/hip_bf16.h>
#include <cstddef>

#define IMW   96
#define HWSZ  (IMW*IMW)       // 9216
#define CTOT  512
#define CHG   256             // channels per group
#define NBATCH 8
#define ROWP  104             // padded LDS row stride (ushorts)
#define XT_LD 280             // mix staging stride (ushorts)
#define TO_LD 76              // mix transpose stride (ushorts): 152B, 8/16B aligned

typedef short  bf16x8  __attribute__((ext_vector_type(8)));
typedef float  f32x4   __attribute__((ext_vector_type(4)));
typedef unsigned short ushort8v __attribute__((ext_vector_type(8)));

// packed f32x2 -> bf16x2 (v_cvt_pk_bf16_f32, RNE); lo in bits 0..15
__device__ __forceinline__ unsigned pk2(float lo, float hi) {
    union { __hip_bfloat162 h; unsigned u; } v;
    v.h = __float22bfloat162_rn(make_float2(lo, hi));
    return v.u;
}
__device__ __forceinline__ float bf2f(ushort u) {
    union { unsigned u; float f; } v; v.u = ((unsigned)u) << 16;
    return v.f;
}

// ---- tiny: convert w_mix (2x256x256 fp32) to bf16 once per launch ----
__global__ __launch_bounds__(256) void wconv_kernel(const float* __restrict__ w,
                                                    unsigned* __restrict__ wbf) {
    const int i = blockIdx.x * 256 + threadIdx.x;   // pair index
    wbf[i] = pk2(w[2 * i], w[2 * i + 1]);
}

// ---------------- kernel 1: grouped 1x1 conv + shuffle, bf16 MFMA ----------------
// XB=0: x fp32; XB=1: x bf16 state. Epilogue transposes acc through LDS so global
// stores are 8 x 128B fully-covered lines per instruction. (round-8 version, ~14us)
template<bool XB>
__global__ __launch_bounds__(256, 3) void mix_mfma(
    const void* __restrict__ xin, const ushort* __restrict__ wbf,
    ushort* __restrict__ h)
{
    const int pt = blockIdx.x * 64;
    const int b  = blockIdx.y >> 1, g = blockIdx.y & 1;
    const size_t xoff = ((size_t)b * CTOT + (size_t)g * CHG) * HWSZ;
    const ushort* wg = wbf + (size_t)g * CHG * CHG;
    ushort* hb = h + (size_t)b * CTOT * HWSZ;

    __shared__ ushort XtBuf[19456];   // 38.9 KB: staging [64][280] then transpose [256][76]

    const int t  = threadIdx.x;
    const int tq = t & 15;             // pixel quad
    const int tk = t >> 4;             // k-pair selector

    #pragma unroll
    for (int it = 0; it < 8; ++it) {   // covers all k
        const int k = 32 * it + 2 * tk;
        unsigned u0, u1, u2, u3;
        if constexpr (XB) {
            const ushort* xb = (const ushort*)xin + xoff;
            ushort4 a0 = *(const ushort4*)&xb[(size_t)k       * HWSZ + pt + 4 * tq];
            ushort4 a1 = *(const ushort4*)&xb[(size_t)(k + 1) * HWSZ + pt + 4 * tq];
            u0 = (unsigned)a0.x | ((unsigned)a1.x << 16);
            u1 = (unsigned)a0.y | ((unsigned)a1.y << 16);
            u2 = (unsigned)a0.z | ((unsigned)a1.z << 16);
            u3 = (unsigned)a0.w | ((unsigned)a1.w << 16);
        } else {
            const float* xb = (const float*)xin + xoff;
            float4 a0 = *(const float4*)&xb[(size_t)k       * HWSZ + pt + 4 * tq];
            float4 a1 = *(const float4*)&xb[(size_t)(k + 1) * HWSZ + pt + 4 * tq];
            u0 = pk2(a0.x, a1.x);
            u1 = pk2(a0.y, a1.y);
            u2 = pk2(a0.z, a1.z);
            u3 = pk2(a0.w, a1.w);
        }
        *(unsigned*)&XtBuf[(4 * tq + 0) * XT_LD + k] = u0;
        *(unsigned*)&XtBuf[(4 * tq + 1) * XT_LD + k] = u1;
        *(unsigned*)&XtBuf[(4 * tq + 2) * XT_LD + k] = u2;
        *(unsigned*)&XtBuf[(4 * tq + 3) * XT_LD + k] = u3;
    }
    __syncthreads();

    const int wv  = t >> 6;            // wave -> 64 o-channels
    const int ln  = t & 63;
    const int row = ln & 15;
    const int kb  = ln >> 4;

    f32x4 acc[4][4];
    #pragma unroll
    for (int m = 0; m < 4; ++m)
        #pragma unroll
        for (int n = 0; n < 4; ++n)
            acc[m][n] = (f32x4){0.f, 0.f, 0.f, 0.f};

    #pragma unroll
    for (int ks = 0; ks < 8; ++ks) {
        bf16x8 Xf[4], Wf[4];
        #pragma unroll
        for (int m = 0; m < 4; ++m)    // A operand: X^T[pixel=16m+row][k]
            Xf[m] = *(const bf16x8*)&XtBuf[(16 * m + row) * XT_LD + 32 * ks + 8 * kb];
        #pragma unroll
        for (int n = 0; n < 4; ++n)    // B operand: W^T[k][o]
            Wf[n] = *(const bf16x8*)&wg[(size_t)(64 * wv + 16 * n + row) * CHG + 32 * ks + 8 * kb];
        #pragma unroll
        for (int m = 0; m < 4; ++m)
            #pragma unroll
            for (int n = 0; n < 4; ++n)
                acc[m][n] = __builtin_amdgcn_mfma_f32_16x16x32_bf16(Xf[m], Wf[n], acc[m][n], 0, 0, 0);
    }

    // epilogue: acc -> LDS transpose [o][pixel] -> coalesced 128B-line stores
    __syncthreads();   // all Xf reads done; reuse buffer
    #pragma unroll
    for (int m = 0; m < 4; ++m) {
        #pragma unroll
        for (int n = 0; n < 4; ++n) {
            const int o = 64 * wv + 16 * n + row;
            *(uint2*)&XtBuf[o * TO_LD + 16 * m + 4 * kb] =
                make_uint2(pk2(acc[m][n][0], acc[m][n][1]), pk2(acc[m][n][2], acc[m][n][3]));
        }
    }
    __syncthreads();
    const int o8i = t >> 3;            // 0..31
    const int px8 = (t & 7) * 8;       // 0..56
    #pragma unroll
    for (int j = 0; j < 8; ++j) {
        const int o2 = o8i + 32 * j;
        const int c  = 2 * o2 + g;     // channel shuffle folded
        uint4 v = *(const uint4*)&XtBuf[o2 * TO_LD + px8];
        *(uint4*)&hb[(size_t)c * HWSZ + pt + px8] = v;
    }
}

// ------- kernel 2: fused dwconv3x3 + IN + affine + GELU + gate + update -------
// (round-7 version, 117us) 576 threads: 96 rows x 6 segs x 16 px.
// XB: cur bf16; PB: prev bf16; EQ: prev==cur (skip load); OB: out bf16.
// Alias safety (t2: out==prev buffer): pv read is the thread's OWN px and the
// store value depends on it -> same-thread read-before-write.
template<bool XB, bool PB, bool EQ, bool OB>
__global__ __launch_bounds__(576, 4) void plane_kernel(
    const ushort* __restrict__ hmid,
    const void* __restrict__ xcur, const void* __restrict__ xprev,
    const float* __restrict__ wdw,
    const float* __restrict__ gammas, const float* __restrict__ betas,
    const float* __restrict__ alphap, int t,
    void* __restrict__ out)
{
    const int plane = blockIdx.x;          // b*512 + c
    const int c = plane & (CTOT - 1);
    const ushort* hp = hmid + (size_t)plane * HWSZ;

    __shared__ ushort sh[IMW * ROWP];   // ~20 KB h plane (bf16)
    __shared__ ushort sx[IMW * ROWP];   // ~20 KB x plane (bf16)
    __shared__ float  red[32];

    const int tid = threadIdx.x;
    const int r   = tid / 6;            // row 0..95
    const int s6  = tid - r * 6;        // segment 0..5
    const int x0  = s6 * 16;
    const int pix = r * IMW + x0;

    // --- pre-barrier: own-x load (packed), h stage, sx stage ---
    ushort8v xr[2];     // raw bf16 x (XB)
    float4   xf[4];     // raw fp32 x (!XB)
    if constexpr (XB) {
        const ushort8v* s = (const ushort8v*)((const ushort*)xcur + (size_t)plane * HWSZ + pix);
        xr[0] = s[0]; xr[1] = s[1];
    } else {
        const float4* s = (const float4*)((const float*)xcur + (size_t)plane * HWSZ + pix);
        #pragma unroll
        for (int q = 0; q < 4; ++q) xf[q] = s[q];
    }
    // stage h plane (2 x 16B per thread)
    {
        const uint4* src = (const uint4*)(hp + (size_t)r * IMW);
        uint4* dst = (uint4*)(sh + r * ROWP);
        dst[2 * s6]     = src[2 * s6];
        dst[2 * s6 + 1] = src[2 * s6 + 1];
    }
    // stage x plane bf16
    {
        if constexpr (XB) {
            ushort8v* dst = (ushort8v*)(sx + r * ROWP + x0);
            dst[0] = xr[0]; dst[1] = xr[1];          // raw copy, no VALU
        } else {
            uint4* dst = (uint4*)(sx + r * ROWP + x0);
            dst[0] = make_uint4(pk2(xf[0].x, xf[0].y), pk2(xf[0].z, xf[0].w),
                                pk2(xf[1].x, xf[1].y), pk2(xf[1].z, xf[1].w));
            dst[1] = make_uint4(pk2(xf[2].x, xf[2].y), pk2(xf[2].z, xf[2].w),
                                pk2(xf[3].x, xf[3].y), pk2(xf[3].z, xf[3].w));
        }
    }
    float w9[9];
    #pragma unroll
    for (int i = 0; i < 9; ++i) w9[i] = wdw[c * 9 + i];

    __syncthreads();   // barrier 1: LDS staged

    // issue pv loads now (packed regs); consumed only in tail
    ushort8v pr[2];
    float4   pf[4];
    if constexpr (!EQ) {
        if constexpr (PB) {
            const ushort8v* s = (const ushort8v*)((const ushort*)xprev + (size_t)plane * HWSZ + pix);
            pr[0] = s[0]; pr[1] = s[1];
        } else {
            const float4* s = (const float4*)((const float*)xprev + (size_t)plane * HWSZ + pix);
            #pragma unroll
            for (int q = 0; q < 4; ++q) pf[q] = s[q];
        }
    }

    // depthwise 3x3 from LDS row windows
    float conv[16];
    #pragma unroll
    for (int i = 0; i < 16; ++i) conv[i] = 0.f;
    #pragma unroll
    for (int ky = 0; ky < 3; ++ky) {
        const int yy = r + ky - 1;
        if ((unsigned)yy < IMW) {
            const ushort* rp = sh + yy * ROWP + x0;
            float f[18];
            ushort8v a = *(const ushort8v*)rp;
            ushort8v bq = *(const ushort8v*)(rp + 8);
            f[0]  = (s6 > 0) ? bf2f(rp[-1]) : 0.f;
            f[17] = (s6 < 5) ? bf2f(rp[16]) : 0.f;
            #pragma unroll
            for (int j = 0; j < 8; ++j) { f[1 + j] = bf2f(a[j]); f[9 + j] = bf2f(bq[j]); }
            const float w0 = w9[3 * ky], w1 = w9[3 * ky + 1], w2 = w9[3 * ky + 2];
            #pragma unroll
            for (int i = 0; i < 16; ++i)
                conv[i] = fmaf(w0, f[i], fmaf(w1, f[i + 1], fmaf(w2, f[i + 2], conv[i])));
        }
    }

    // materialize xv fp32
    float xv[16];
    if constexpr (XB) {
        #pragma unroll
        for (int j = 0; j < 8; ++j) { xv[j] = bf2f(xr[0][j]); xv[8 + j] = bf2f(xr[1][j]); }
    } else {
        #pragma unroll
        for (int q = 0; q < 4; ++q)
            #pragma unroll
            for (int j = 0; j < 4; ++j) xv[4 * q + j] = xf[q][j];
    }

    // gate accumulation gt (before the reduction barrier -> overlaps the wait)
    float gt[16];
    #pragma unroll
    for (int half = 0; half < 2; ++half) {
        const int xb = x0 + 8 * half;
        float up[3][8];
        #pragma unroll
        for (int dd = 0; dd < 3; ++dd) {
            int ym = r - (1 << dd); if (ym < 0) ym += IMW;
            ushort8v a = *(const ushort8v*)(sx + ym * ROWP + xb);
            #pragma unroll
            for (int j = 0; j < 8; ++j) up[dd][j] = bf2f(a[j]);
        }
        float lw[8];
        if (half == 0) {
            const int lx = (x0 == 0) ? (IMW - 8) : (x0 - 8);
            ushort8v h0 = *(const ushort8v*)(sx + r * ROWP + lx);
            #pragma unroll
            for (int j = 0; j < 8; ++j) lw[j] = bf2f(h0[j]);
        }
        #pragma unroll
        for (int i = 0; i < 8; ++i) {
            const int ii = 8 * half + i;
            const float xvi = xv[ii];
            float g = 0.f;
            #pragma unroll
            for (int dd = 0; dd < 3; ++dd) {
                const int d = 1 << dd;
                const float left = (i - d >= 0) ? xv[ii - d]
                                 : (half ? xv[ii - d] : lw[8 + i - d]);
                g += fabsf(xvi - up[dd][i]) + fabsf(xvi - left);
            }
            gt[ii] = g;
        }
    }

    // instance-norm moments
    float s = 0.f, s2 = 0.f;
    #pragma unroll
    for (int i = 0; i < 16; ++i) { s += conv[i]; s2 = fmaf(conv[i], conv[i], s2); }
    #pragma unroll
    for (int off = 32; off; off >>= 1) {
        s  += __shfl_down(s, off, 64);
        s2 += __shfl_down(s2, off, 64);
    }
    const int wv = tid >> 6;           // 0..8
    if ((tid & 63) == 0) { red[wv] = s; red[16 + wv] = s2; }
    __syncthreads();                   // barrier 2
    float ssum = 0.f, s2sum = 0.f;
    #pragma unroll
    for (int i = 0; i < 9; ++i) { ssum += red[i]; s2sum += red[16 + i]; }
    const float mu   = ssum * (1.f / HWSZ);
    const float var  = fmaxf(s2sum * (1.f / HWSZ) - mu * mu, 0.f);
    const float rsig = rsqrtf(var + 1e-5f);
    const float ga = gammas[t * CTOT + c] * rsig;
    const float be = betas[t * CTOT + c];
    const float alpha = alphap[0];

    // tail: gate finish + GELU + residual update
    #pragma unroll
    for (int half = 0; half < 2; ++half) {
        float pvh[8];
        if constexpr (EQ) {
            #pragma unroll
            for (int j = 0; j < 8; ++j) pvh[j] = xv[8 * half + j];
        } else if constexpr (PB) {
            #pragma unroll
            for (int j = 0; j < 8; ++j) pvh[j] = bf2f(pr[half][j]);
        } else {
            #pragma unroll
            for (int j = 0; j < 4; ++j) { pvh[j] = pf[2 * half][j]; pvh[4 + j] = pf[2 * half + 1][j]; }
        }
        float o8[8];
        #pragma unroll
        for (int i = 0; i < 8; ++i) {
            const int ii = 8 * half + i;
            const float xvi = xv[ii];
            const float eg   = __expf(gt[ii] * (-1.f / 3.f));
            const float gate = __builtin_amdgcn_rcpf(1.f + eg);
            const float hn  = fmaf(conv[ii] - mu, ga, be);
            const float z   = 0.7978845608f * fmaf(0.044715f * hn * hn, hn, hn);
            const float e2  = __expf(2.f * z);
            const float th  = 1.f - 2.f * __builtin_amdgcn_rcpf(e2 + 1.f);
            const float gel = 0.5f * hn * (1.f + th);
            o8[i] = fmaf(alpha, xvi - pvh[i], fmaf(gate, gel, xvi));
        }
        if constexpr (OB) {
            uint4 u = make_uint4(pk2(o8[0], o8[1]), pk2(o8[2], o8[3]),
                                 pk2(o8[4], o8[5]), pk2(o8[6], o8[7]));
            *(uint4*)((ushort*)out + (size_t)plane * HWSZ + pix + 8 * half) = u;
        } else {
            float* op = (float*)out + (size_t)plane * HWSZ + pix + 8 * half;
            *(float4*)op       = make_float4(o8[0], o8[1], o8[2], o8[3]);
            *(float4*)(op + 4) = make_float4(o8[4], o8[5], o8[6], o8[7]);
        }
    }
}

extern "C" void kernel_launch(void* const* d_in, const int* in_sizes, int n_in,
                              void* d_out, int out_size, void* d_ws, size_t ws_size,
                              hipStream_t stream) {
    const float* x0     = (const float*)d_in[0];
    const float* wmix   = (const float*)d_in[1];
    const float* wdw    = (const float*)d_in[2];
    const float* gammas = (const float*)d_in[3];
    const float* betas  = (const float*)d_in[4];
    const float* alphap = (const float*)d_in[5];

    const size_t NELEM = (size_t)NBATCH * CTOT * HWSZ;   // 37,748,736
    float*  D   = (float*)d_out;                          // final x4 (fp32)
    char*   ws  = (char*)d_ws;
    ushort* X1b = (ushort*)ws;                            // x1, then x3 (bf16)
    ushort* X2b = (ushort*)(ws + NELEM * 2);              // x2 (bf16)
    ushort* Hb  = (ushort*)(ws + NELEM * 4);              // mix output (bf16)
    ushort* Wbf = (ushort*)(ws + NELEM * 6);              // w_mix bf16 (256 KB)

    wconv_kernel<<<256, 256, 0, stream>>>(wmix, (unsigned*)Wbf);

    dim3 mgrid(HWSZ / 64, NBATCH * 2);   // (144, 16)
    const int pgrid = NBATCH * CTOT;     // 4096

    // t=0: cur=prev=x0 (fp32) -> X1b (bf16)
    mix_mfma<false><<<mgrid, 256, 0, stream>>>(x0, Wbf, Hb);
    plane_kernel<false, false, true, true><<<pgrid, 576, 0, stream>>>(
        Hb, x0, x0, wdw, gammas, betas, alphap, 0, X1b);
    // t=1: cur=X1b prev=x0 (fp32) -> X2b (bf16)
    mix_mfma<true><<<mgrid, 256, 0, stream>>>(X1b, Wbf, Hb);
    plane_kernel<true, false, false, true><<<pgrid, 576, 0, stream>>>(
        Hb, X1b, x0, wdw, gammas, betas, alphap, 1, X2b);
    // t=2: cur=X2b prev=X1b -> X1b (same-thread read-before-write alias)
    mix_mfma<true><<<mgrid, 256, 0, stream>>>(X2b, Wbf, Hb);
    plane_kernel<true, true, false, true><<<pgrid, 576, 0, stream>>>(
        Hb, X2b, X1b, wdw, gammas, betas, alphap, 2, X1b);
    // t=3: cur=X1b(x3) prev=X2b -> D (fp32 final)
    mix_mfma<true><<<mgrid, 256, 0, stream>>>(X1b, Wbf, Hb);
    plane_kernel<true, true, false, false><<<pgrid, 576, 0, stream>>>(
        Hb, X1b, X2b, wdw, gammas, betas, alphap, 3, D);
}

// Round 11
// 556.243 us; speedup vs baseline: 1.7554x; 1.1440x over previous
//
#include <hip/hip_runtime.h>
#include <hip/hip_bf16.h>
#include <cstddef>

#define IMW   96
#define HWSZ  (IMW*IMW)       // 9216
#define CTOT  512
#define CHG   256             // channels per group
#define NBATCH 8
#define ROWP  104             // padded LDS row stride (ushorts)
#define XT_LD 280             // mix staging stride (ushorts)
#define TO_LD 76              // mix transpose stride (ushorts)

typedef short  bf16x8  __attribute__((ext_vector_type(8)));
typedef float  f32x4   __attribute__((ext_vector_type(4)));
typedef unsigned short ushort8v __attribute__((ext_vector_type(8)));
typedef _Float16 f16x2 __attribute__((ext_vector_type(2)));
typedef __fp16   fp16x2b __attribute__((ext_vector_type(2)));   // builtin return type

union U32H2 { unsigned u; f16x2 h; fp16x2b hb; };

// packed f32x2 -> bf16x2 (v_cvt_pk_bf16_f32, RNE); lo in bits 0..15
__device__ __forceinline__ unsigned pk2(float lo, float hi) {
    union { __hip_bfloat162 h; unsigned u; } v;
    v.h = __float22bfloat162_rn(make_float2(lo, hi));
    return v.u;
}
// packed f32x2 -> fp16x2 (v_cvt_pkrtz_f16_f32)
__device__ __forceinline__ unsigned pkh(float lo, float hi) {
    U32H2 v; v.hb = __builtin_amdgcn_cvt_pkrtz(lo, hi); return v.u;
}
__device__ __forceinline__ f16x2 h2(unsigned u) { U32H2 v; v.u = u; return v.h; }
__device__ __forceinline__ unsigned h2u(f16x2 h) { U32H2 v; v.h = h; return v.u; }
__device__ __forceinline__ float bf2f(ushort u) {
    union { unsigned u; float f; } v; v.u = ((unsigned)u) << 16;
    return v.f;
}

// ---- tiny: convert w_mix (2x256x256 fp32) to bf16 once per launch ----
__global__ __launch_bounds__(256) void wconv_kernel(const float* __restrict__ w,
                                                    unsigned* __restrict__ wbf) {
    const int i = blockIdx.x * 256 + threadIdx.x;   // pair index
    wbf[i] = pk2(w[2 * i], w[2 * i + 1]);
}

// ---------------- kernel 1: grouped 1x1 conv + shuffle, bf16 MFMA ----------------
// XB=0: x fp32; XB=1: x bf16 state. Output h is FP16 (plane conv runs packed fp16).
template<bool XB>
__global__ __launch_bounds__(256, 3) void mix_mfma(
    const void* __restrict__ xin, const ushort* __restrict__ wbf,
    ushort* __restrict__ h)
{
    const int pt = blockIdx.x * 64;
    const int b  = blockIdx.y >> 1, g = blockIdx.y & 1;
    const size_t xoff = ((size_t)b * CTOT + (size_t)g * CHG) * HWSZ;
    const ushort* wg = wbf + (size_t)g * CHG * CHG;
    ushort* hb = h + (size_t)b * CTOT * HWSZ;

    __shared__ ushort XtBuf[19456];   // staging [64][280] then transpose [256][76]

    const int t  = threadIdx.x;
    const int tq = t & 15;             // pixel quad
    const int tk = t >> 4;             // k-pair selector

    #pragma unroll
    for (int it = 0; it < 8; ++it) {   // covers all k
        const int k = 32 * it + 2 * tk;
        unsigned u0, u1, u2, u3;
        if constexpr (XB) {
            const ushort* xb = (const ushort*)xin + xoff;
            ushort4 a0 = *(const ushort4*)&xb[(size_t)k       * HWSZ + pt + 4 * tq];
            ushort4 a1 = *(const ushort4*)&xb[(size_t)(k + 1) * HWSZ + pt + 4 * tq];
            u0 = (unsigned)a0.x | ((unsigned)a1.x << 16);
            u1 = (unsigned)a0.y | ((unsigned)a1.y << 16);
            u2 = (unsigned)a0.z | ((unsigned)a1.z << 16);
            u3 = (unsigned)a0.w | ((unsigned)a1.w << 16);
        } else {
            const float* xb = (const float*)xin + xoff;
            float4 a0 = *(const float4*)&xb[(size_t)k       * HWSZ + pt + 4 * tq];
            float4 a1 = *(const float4*)&xb[(size_t)(k + 1) * HWSZ + pt + 4 * tq];
            u0 = pk2(a0.x, a1.x);
            u1 = pk2(a0.y, a1.y);
            u2 = pk2(a0.z, a1.z);
            u3 = pk2(a0.w, a1.w);
        }
        *(unsigned*)&XtBuf[(4 * tq + 0) * XT_LD + k] = u0;
        *(unsigned*)&XtBuf[(4 * tq + 1) * XT_LD + k] = u1;
        *(unsigned*)&XtBuf[(4 * tq + 2) * XT_LD + k] = u2;
        *(unsigned*)&XtBuf[(4 * tq + 3) * XT_LD + k] = u3;
    }
    __syncthreads();

    const int wv  = t >> 6;            // wave -> 64 o-channels
    const int ln  = t & 63;
    const int row = ln & 15;
    const int kb  = ln >> 4;

    f32x4 acc[4][4];
    #pragma unroll
    for (int m = 0; m < 4; ++m)
        #pragma unroll
        for (int n = 0; n < 4; ++n)
            acc[m][n] = (f32x4){0.f, 0.f, 0.f, 0.f};

    #pragma unroll
    for (int ks = 0; ks < 8; ++ks) {
        bf16x8 Xf[4], Wf[4];
        #pragma unroll
        for (int m = 0; m < 4; ++m)
            Xf[m] = *(const bf16x8*)&XtBuf[(16 * m + row) * XT_LD + 32 * ks + 8 * kb];
        #pragma unroll
        for (int n = 0; n < 4; ++n)
            Wf[n] = *(const bf16x8*)&wg[(size_t)(64 * wv + 16 * n + row) * CHG + 32 * ks + 8 * kb];
        #pragma unroll
        for (int m = 0; m < 4; ++m)
            #pragma unroll
            for (int n = 0; n < 4; ++n)
                acc[m][n] = __builtin_amdgcn_mfma_f32_16x16x32_bf16(Xf[m], Wf[n], acc[m][n], 0, 0, 0);
    }

    // epilogue: acc -> LDS transpose [o][pixel] (fp16) -> coalesced 128B-line stores
    __syncthreads();
    #pragma unroll
    for (int m = 0; m < 4; ++m) {
        #pragma unroll
        for (int n = 0; n < 4; ++n) {
            const int o = 64 * wv + 16 * n + row;
            *(uint2*)&XtBuf[o * TO_LD + 16 * m + 4 * kb] =
                make_uint2(pkh(acc[m][n][0], acc[m][n][1]), pkh(acc[m][n][2], acc[m][n][3]));
        }
    }
    __syncthreads();
    const int o8i = t >> 3;            // 0..31
    const int px8 = (t & 7) * 8;       // 0..56
    #pragma unroll
    for (int j = 0; j < 8; ++j) {
        const int o2 = o8i + 32 * j;
        const int c  = 2 * o2 + g;     // channel shuffle folded
        uint4 v = *(const uint4*)&XtBuf[o2 * TO_LD + px8];
        *(uint4*)&hb[(size_t)c * HWSZ + pt + px8] = v;
    }
}

// ------- kernel 2: fused dwconv3x3 + IN + affine + GELU + gate + update -------
// 576 threads: 96 rows x 6 segs x 16 px. h (fp16) and x (fp16) staged in LDS;
// conv + gate run in PACKED fp16 (2 px/instruction). State I/O stays bf16/fp32.
// Alias safety (t2: out==prev buffer): pv read is the thread's OWN px and the
// store value depends on it -> same-thread read-before-write.
template<bool XB, bool PB, bool EQ, bool OB>
__global__ __launch_bounds__(576, 4) void plane_kernel(
    const ushort* __restrict__ hmid,
    const void* __restrict__ xcur, const void* __restrict__ xprev,
    const float* __restrict__ wdw,
    const float* __restrict__ gammas, const float* __restrict__ betas,
    const float* __restrict__ alphap, int t,
    void* __restrict__ out)
{
    const int plane = blockIdx.x;          // b*512 + c
    const int c = plane & (CTOT - 1);
    const ushort* hp = hmid + (size_t)plane * HWSZ;

    __shared__ ushort sh[IMW * ROWP];   // ~20 KB h plane (fp16)
    __shared__ ushort sx[IMW * ROWP];   // ~20 KB x plane (fp16)
    __shared__ float  red[32];

    const int tid = threadIdx.x;
    const int r   = tid / 6;            // row 0..95
    const int s6  = tid - r * 6;        // segment 0..5
    const int x0  = s6 * 16;
    const int pix = r * IMW + x0;

    // --- pre-barrier: own-x load, xv materialize, h stage, sx stage (fp16) ---
    ushort8v xr[2];     // raw bf16 x (XB)
    float4   xf[4];     // raw fp32 x (!XB)
    float xv[16];
    if constexpr (XB) {
        const ushort8v* s = (const ushort8v*)((const ushort*)xcur + (size_t)plane * HWSZ + pix);
        xr[0] = s[0]; xr[1] = s[1];
        #pragma unroll
        for (int j = 0; j < 8; ++j) { xv[j] = bf2f(xr[0][j]); xv[8 + j] = bf2f(xr[1][j]); }
    } else {
        const float4* s = (const float4*)((const float*)xcur + (size_t)plane * HWSZ + pix);
        #pragma unroll
        for (int q = 0; q < 4; ++q) xf[q] = s[q];
        #pragma unroll
        for (int q = 0; q < 4; ++q)
            #pragma unroll
            for (int j = 0; j < 4; ++j) xv[4 * q + j] = xf[q][j];
    }
    // stage h plane (raw copy, already fp16 from mix)
    {
        const uint4* src = (const uint4*)(hp + (size_t)r * IMW);
        uint4* dst = (uint4*)(sh + r * ROWP);
        dst[2 * s6]     = src[2 * s6];
        dst[2 * s6 + 1] = src[2 * s6 + 1];
    }
    // stage x plane fp16 (bf16->fp16 is exact)
    {
        uint4* dst = (uint4*)(sx + r * ROWP + x0);
        dst[0] = make_uint4(pkh(xv[0], xv[1]),  pkh(xv[2], xv[3]),
                            pkh(xv[4], xv[5]),  pkh(xv[6], xv[7]));
        dst[1] = make_uint4(pkh(xv[8], xv[9]),  pkh(xv[10], xv[11]),
                            pkh(xv[12], xv[13]), pkh(xv[14], xv[15]));
    }
    float w9[9];
    #pragma unroll
    for (int i = 0; i < 9; ++i) w9[i] = wdw[c * 9 + i];

    __syncthreads();   // barrier 1: LDS staged

    // issue pv loads now; consumed only in tail
    ushort8v pr[2];
    float4   pf[4];
    if constexpr (!EQ) {
        if constexpr (PB) {
            const ushort8v* s = (const ushort8v*)((const ushort*)xprev + (size_t)plane * HWSZ + pix);
            pr[0] = s[0]; pr[1] = s[1];
        } else {
            const float4* s = (const float4*)((const float*)xprev + (size_t)plane * HWSZ + pix);
            #pragma unroll
            for (int q = 0; q < 4; ++q) pf[q] = s[q];
        }
    }

    // ---- depthwise 3x3, packed fp16: 2 px per op ----
    f16x2 cp[8];
    #pragma unroll
    for (int m = 0; m < 8; ++m) cp[m] = (f16x2){(_Float16)0.f, (_Float16)0.f};
    #pragma unroll
    for (int ky = 0; ky < 3; ++ky) {
        const int yy = r + ky - 1;
        if ((unsigned)yy < IMW) {
            const ushort* rp = sh + yy * ROWP + x0;
            uint4 ga = *(const uint4*)rp;
            uint4 gb = *(const uint4*)(rp + 8);
            unsigned gg[8] = {ga.x, ga.y, ga.z, ga.w, gb.x, gb.y, gb.z, gb.w};
            const unsigned L = (s6 > 0) ? *(const unsigned*)(rp - 2)  : 0u;  // (h[-2],h[-1]) zero-pad
            const unsigned R = (s6 < 5) ? *(const unsigned*)(rp + 16) : 0u;  // (h[16],h[17])
            unsigned S[9];
            S[0] = (L >> 16) | (gg[0] << 16);
            #pragma unroll
            for (int m = 1; m < 8; ++m) S[m] = (gg[m - 1] >> 16) | (gg[m] << 16);
            S[8] = (gg[7] >> 16) | (R << 16);
            const _Float16 w0 = (_Float16)w9[3 * ky], w1 = (_Float16)w9[3 * ky + 1],
                           w2 = (_Float16)w9[3 * ky + 2];
            const f16x2 w0_2 = (f16x2){w0, w0}, w1_2 = (f16x2){w1, w1}, w2_2 = (f16x2){w2, w2};
            #pragma unroll
            for (int m = 0; m < 8; ++m)
                cp[m] = cp[m] + w0_2 * h2(S[m]) + w1_2 * h2(gg[m]) + w2_2 * h2(S[m + 1]);
        }
    }
    float conv[16];
    #pragma unroll
    for (int m = 0; m < 8; ++m) { conv[2 * m] = (float)cp[m][0]; conv[2 * m + 1] = (float)cp[m][1]; }

    // ---- gate accumulation, packed fp16 (roll semantics: wrap) ----
    f16x2 gt2[8];
    #pragma unroll
    for (int m = 0; m < 8; ++m) gt2[m] = (f16x2){(_Float16)0.f, (_Float16)0.f};
    {
        const ushort* xrp = sx + r * ROWP + x0;
        uint4 xa = *(const uint4*)xrp;
        uint4 xb2 = *(const uint4*)(xrp + 8);
        unsigned xc[8] = {xa.x, xa.y, xa.z, xa.w, xb2.x, xb2.y, xb2.z, xb2.w};
        const int lx1 = (x0 == 0) ? (IMW - 2) : (x0 - 2);
        const int lx2 = (x0 == 0) ? (IMW - 4) : (x0 - 4);
        const unsigned L1 = *(const unsigned*)(sx + r * ROWP + lx1);  // (x[-2],x[-1])
        const unsigned L2 = *(const unsigned*)(sx + r * ROWP + lx2);  // (x[-4],x[-3])
        // horizontal neighbors
        unsigned p1[8], p2[8], p4[8];
        p1[0] = (L1 >> 16) | (xc[0] << 16);
        #pragma unroll
        for (int m = 1; m < 8; ++m) p1[m] = (xc[m - 1] >> 16) | (xc[m] << 16);
        p2[0] = L1;
        #pragma unroll
        for (int m = 1; m < 8; ++m) p2[m] = xc[m - 1];
        p4[0] = L2; p4[1] = L1;
        #pragma unroll
        for (int m = 2; m < 8; ++m) p4[m] = xc[m - 2];
        #pragma unroll
        for (int m = 0; m < 8; ++m) {
            const f16x2 xcm = h2(xc[m]);
            gt2[m] = gt2[m] + h2(h2u(xcm - h2(p1[m])) & 0x7FFF7FFFu);
            gt2[m] = gt2[m] + h2(h2u(xcm - h2(p2[m])) & 0x7FFF7FFFu);
            gt2[m] = gt2[m] + h2(h2u(xcm - h2(p4[m])) & 0x7FFF7FFFu);
        }
        // vertical neighbors (rows r-1, r-2, r-4, wrapped)
        #pragma unroll
        for (int dd = 0; dd < 3; ++dd) {
            int ym = r - (1 << dd); if (ym < 0) ym += IMW;
            const ushort* vp = sx + ym * ROWP + x0;
            uint4 va = *(const uint4*)vp;
            uint4 vb = *(const uint4*)(vp + 8);
            unsigned vv[8] = {va.x, va.y, va.z, va.w, vb.x, vb.y, vb.z, vb.w};
            #pragma unroll
            for (int m = 0; m < 8; ++m)
                gt2[m] = gt2[m] + h2(h2u(h2(xc[m]) - h2(vv[m])) & 0x7FFF7FFFu);
        }
    }
    float gt[16];
    #pragma unroll
    for (int m = 0; m < 8; ++m) { gt[2 * m] = (float)gt2[m][0]; gt[2 * m + 1] = (float)gt2[m][1]; }

    // ---- instance-norm moments ----
    float s = 0.f, s2 = 0.f;
    #pragma unroll
    for (int i = 0; i < 16; ++i) { s += conv[i]; s2 = fmaf(conv[i], conv[i], s2); }
    #pragma unroll
    for (int off = 32; off; off >>= 1) {
        s  += __shfl_down(s, off, 64);
        s2 += __shfl_down(s2, off, 64);
    }
    const int wv = tid >> 6;           // 0..8
    if ((tid & 63) == 0) { red[wv] = s; red[16 + wv] = s2; }
    __syncthreads();                   // barrier 2
    float ssum = 0.f, s2sum = 0.f;
    #pragma unroll
    for (int i = 0; i < 9; ++i) { ssum += red[i]; s2sum += red[16 + i]; }
    const float mu   = ssum * (1.f / HWSZ);
    const float var  = fmaxf(s2sum * (1.f / HWSZ) - mu * mu, 0.f);
    const float rsig = rsqrtf(var + 1e-5f);
    const float ga = gammas[t * CTOT + c] * rsig;
    const float be = betas[t * CTOT + c];
    const float alpha = alphap[0];

    // ---- tail: fused gate*gelu (single rcp) + residual update ----
    #pragma unroll
    for (int half = 0; half < 2; ++half) {
        float pvh[8];
        if constexpr (EQ) {
            #pragma unroll
            for (int j = 0; j < 8; ++j) pvh[j] = xv[8 * half + j];
        } else if constexpr (PB) {
            #pragma unroll
            for (int j = 0; j < 8; ++j) pvh[j] = bf2f(pr[half][j]);
        } else {
            #pragma unroll
            for (int j = 0; j < 4; ++j) { pvh[j] = pf[2 * half][j]; pvh[4 + j] = pf[2 * half + 1][j]; }
        }
        float o8[8];
        #pragma unroll
        for (int i = 0; i < 8; ++i) {
            const int ii = 8 * half + i;
            const float xvi = xv[ii];
            const float hn  = fmaf(conv[ii] - mu, ga, be);
            const float z2  = 1.5957691216f * fmaf(0.044715f * hn * hn, hn, hn);  // 2z
            const float ea  = __expf(gt[ii] * (-1.f / 3.f));   // gate: sigma(gt/3)
            const float eb  = __expf(-z2);                     // gelu: hn*sigma(2z)
            const float den = (1.f + ea) * (1.f + eb);
            const float gg  = hn * __builtin_amdgcn_rcpf(den); // gate*gelu
            o8[i] = fmaf(alpha, xvi - pvh[i], xvi + gg);
        }
        if constexpr (OB) {
            uint4 u = make_uint4(pk2(o8[0], o8[1]), pk2(o8[2], o8[3]),
                                 pk2(o8[4], o8[5]), pk2(o8[6], o8[7]));
            *(uint4*)((ushort*)out + (size_t)plane * HWSZ + pix + 8 * half) = u;
        } else {
            float* op = (float*)out + (size_t)plane * HWSZ + pix + 8 * half;
            *(float4*)op       = make_float4(o8[0], o8[1], o8[2], o8[3]);
            *(float4*)(op + 4) = make_float4(o8[4], o8[5], o8[6], o8[7]);
        }
    }
}

extern "C" void kernel_launch(void* const* d_in, const int* in_sizes, int n_in,
                              void* d_out, int out_size, void* d_ws, size_t ws_size,
                              hipStream_t stream) {
    const float* x0     = (const float*)d_in[0];
    const float* wmix   = (const float*)d_in[1];
    const float* wdw    = (const float*)d_in[2];
    const float* gammas = (const float*)d_in[3];
    const float* betas  = (const float*)d_in[4];
    const float* alphap = (const float*)d_in[5];

    const size_t NELEM = (size_t)NBATCH * CTOT * HWSZ;   // 37,748,736
    float*  D   = (float*)d_out;                          // final x4 (fp32)
    char*   ws  = (char*)d_ws;
    ushort* X1b = (ushort*)ws;                            // x1, then x3 (bf16)
    ushort* X2b = (ushort*)(ws + NELEM * 2);              // x2 (bf16)
    ushort* Hb  = (ushort*)(ws + NELEM * 4);              // mix output (fp16)
    ushort* Wbf = (ushort*)(ws + NELEM * 6);              // w_mix bf16 (256 KB)

    wconv_kernel<<<256, 256, 0, stream>>>(wmix, (unsigned*)Wbf);

    dim3 mgrid(HWSZ / 64, NBATCH * 2);   // (144, 16)
    const int pgrid = NBATCH * CTOT;     // 4096

    // t=0: cur=prev=x0 (fp32) -> X1b (bf16)
    mix_mfma<false><<<mgrid, 256, 0, stream>>>(x0, Wbf, Hb);
    plane_kernel<false, false, true, true><<<pgrid, 576, 0, stream>>>(
        Hb, x0, x0, wdw, gammas, betas, alphap, 0, X1b);
    // t=1: cur=X1b prev=x0 (fp32) -> X2b (bf16)
    mix_mfma<true><<<mgrid, 256, 0, stream>>>(X1b, Wbf, Hb);
    plane_kernel<true, false, false, true><<<pgrid, 576, 0, stream>>>(
        Hb, X1b, x0, wdw, gammas, betas, alphap, 1, X2b);
    // t=2: cur=X2b prev=X1b -> X1b (same-thread read-before-write alias)
    mix_mfma<true><<<mgrid, 256, 0, stream>>>(X2b, Wbf, Hb);
    plane_kernel<true, true, false, true><<<pgrid, 576, 0, stream>>>(
        Hb, X2b, X1b, wdw, gammas, betas, alphap, 2, X1b);
    // t=3: cur=X1b(x3) prev=X2b -> D (fp32 final)
    mix_mfma<true><<<mgrid, 256, 0, stream>>>(X1b, Wbf, Hb);
    plane_kernel<true, true, false, false><<<pgrid, 576, 0, stream>>>(
        Hb, X1b, X2b, wdw, gammas, betas, alphap, 3, D);
}